// Round 15
// baseline (1132.074 us; speedup 1.0000x reference)
//
#include <hip/hip_runtime.h>
#include <hip/hip_bf16.h>
#include <math.h>

#define BB 64
#define TT 200
#define DD 256
#define HH 512
#define NCOL 3584  // 7*H
#define NGRP 4     // independent batch groups (16 batches each)
#define NBLK (NGRP * 32)  // recurrent blocks, 1 wave each
#define SLOT_BYTES (BB * 128 * 16)  // 64 b x 128 hcol4-units x 16B = 131072

using bf16x8 = __attribute__((ext_vector_type(8))) short;
using f32x4  = __attribute__((ext_vector_type(4))) float;
typedef __attribute__((ext_vector_type(4))) unsigned int u32x4;

// ---- fast device math ----
__device__ __forceinline__ float frcp_(float x) { return __builtin_amdgcn_rcpf(x); }
__device__ __forceinline__ float sigmoidf_(float x) {
    return frcp_(1.0f + __expf(-x));
}
__device__ __forceinline__ float tanhf_(float x) {
    return 1.0f - 2.0f * frcp_(__expf(2.0f * x) + 1.0f);
}
__device__ __forceinline__ float softplusf_(float x) {
    return fmaxf(x, 0.0f) + __logf(1.0f + __expf(-fabsf(x)));
}
__device__ __forceinline__ short f2bf(float f) {
    union { float f; unsigned u; } v; v.f = f;
    unsigned r = v.u + 0x7fff + ((v.u >> 16) & 1);  // RNE
    return (short)(r >> 16);
}
__device__ __forceinline__ unsigned f2bf2(float a, float b) {
    return (unsigned)(unsigned short)f2bf(a) | ((unsigned)(unsigned short)f2bf(b) << 16);
}
__device__ __forceinline__ float bf2f(short s) {
    union { unsigned u; float f; } v; v.u = ((unsigned)(unsigned short)s) << 16;
    return v.f;
}

// device-scope (IC-coherent) 16B load/store: SGPR base + VGPR 32b offset
__device__ __forceinline__ u32x4 ld_unit_sc1(const void* sbase, unsigned voff) {
    u32x4 r;
    asm volatile("global_load_dwordx4 %0, %1, %2 sc1"
                 : "=v"(r) : "v"(voff), "s"(sbase) : "memory");
    return r;  // NOT ready until an explicit s_waitcnt!
}
__device__ __forceinline__ void st_unit_sc1(void* sbase, unsigned voff, u32x4 v) {
    asm volatile("global_store_dwordx4 %0, %1, %2 sc1"
                 :: "v"(voff), "v"(v), "s"(sbase) : "memory");
}

// input (B,T,D) fp32 -> Xbf (B*T, D) bf16
__global__ __launch_bounds__(256) void convert_x_kernel(
    const float* __restrict__ in, short* __restrict__ Xbf)
{
    int idx = blockIdx.x * 256 + threadIdx.x;  // < 819200
    float4 v = ((const float4*)in)[idx];
    short4 s;
    s.x = f2bf(v.x); s.y = f2bf(v.y); s.z = f2bf(v.z); s.w = f2bf(v.w);
    ((short4*)Xbf)[idx] = s;
}

// Wx (D, NCOL) fp32 -> WxP packed B-fragments
__global__ __launch_bounds__(256) void pack_wx_kernel(
    const float* __restrict__ Wx, short* __restrict__ WxP)
{
    int idx = blockIdx.x * 256 + threadIdx.x;  // < 917504
    int jj = idx & 7, lane = (idx >> 3) & 63, kt = (idx >> 9) & 7, nt = idx >> 12;
    int k = kt * 32 + ((lane >> 4) << 3) + jj;
    int col = nt * 16 + (lane & 15);
    WxP[idx] = f2bf(Wx[(size_t)k * NCOL + col]);
}

// Wh (H, NCOL) fp32 -> WhP packed A-fragments grouped per (j0, gate)
__global__ __launch_bounds__(256) void pack_wh_kernel(
    const float* __restrict__ Wh, short* __restrict__ WhP)
{
    int idx = blockIdx.x * 256 + threadIdx.x;  // < 1835008
    int jj = idx & 7, lane = (idx >> 3) & 63, kt = (idx >> 9) & 15;
    int gj = idx >> 13;  // j0*7 + g
    int g = gj % 7, j0 = gj / 7;
    int k = kt * 32 + ((lane >> 4) << 3) + jj;
    int col = g * HH + j0 * 16 + (lane & 15);
    WhP[idx] = f2bf(Wh[(size_t)k * NCOL + col]);
}

// GEMM1: Xb[row][col] = bf16( Xbf(row,:) @ Wx(:,col) + bias[col] )
// Widened: each block does 64 rows x 128 cols (8 acc frags/wave, 2x ILP).
__global__ __launch_bounds__(256) void precompute_kernel(
    const short* __restrict__ Xbf, const short* __restrict__ WxP,
    const float* __restrict__ bias, short* __restrict__ Xb)
{
    const int tid = threadIdx.x;
    const int lane = tid & 63;
    const int w = tid >> 6;
    const int nb = blockIdx.x;   // 0..27
    const int mb = blockIdx.y;   // 0..199

    f32x4 acc[8];
    #pragma unroll
    for (int i = 0; i < 8; ++i) acc[i] = (f32x4){0.f, 0.f, 0.f, 0.f};

    const int rowA = mb * 64 + w * 16 + (lane & 15);
    const short* __restrict__ ha = Xbf + (size_t)rowA * DD + ((lane >> 4) << 3);
    const short* __restrict__ wbase = WxP + ((size_t)(nb * 8) * 512 + lane) * 8;

    #pragma unroll
    for (int kt = 0; kt < 8; ++kt) {
        bf16x8 a = *(const bf16x8*)(ha + kt * 32);
        #pragma unroll
        for (int i = 0; i < 8; ++i) {
            bf16x8 b = *(const bf16x8*)(wbase + i * 4096 + kt * 512);
            acc[i] = __builtin_amdgcn_mfma_f32_16x16x32_bf16(a, b, acc[i], 0, 0, 0);
        }
    }

    const int colL = lane & 15;
    const int rBase = mb * 64 + w * 16 + ((lane >> 4) << 2);
    #pragma unroll
    for (int i = 0; i < 8; ++i) {
        const int col = (nb * 8 + i) * 16 + colL;
        const float bv = bias[col];
        #pragma unroll
        for (int r = 0; r < 4; ++r) {
            Xb[(size_t)(rBase + r) * NCOL + col] = f2bf(acc[i][r] + bv);
        }
    }
}

// Persistent recurrent kernel: 128 single-wave blocks = 4 independent
// groups x 32 blocks (R14 structure). h exchange: LL self-validating 16B
// units [2xbf16|seq|2xbf16|seq] in 2 parity slots. Producer = ONE sc1
// store, no drain/flag. Consumer polls its 32 units; the successful poll
// IS the h load (data lands directly in the MFMA B-operand registers).
// Queue discipline: poll always meets a clean queue (outs/prefetch retire
// under GEMM; publish is the only VMEM op between epilogue and next poll).
__global__ __launch_bounds__(64, 1) void recurrent_kernel(
    const short* __restrict__ Xb,    // (B*T, NCOL) bf16
    const short* __restrict__ WhP,   // packed A-frags
    const float* __restrict__ dur,   // (B, T)
    unsigned* __restrict__ hslots,   // 2 slots x (64 b x 128 units) x 16B
    float* __restrict__ out)         // (4, B, T, H)
{
    __shared__ short whL[7 * 16 * 64 * 8];  // 114688 B

    const int lane = threadIdx.x;           // single wave
    const int grp = blockIdx.x >> 5;        // 0..3
    const int j0 = blockIdx.x & 31;         // hcol tile

    // ---- stage Wh block slice into LDS (one time) ----
    {
        const bf16x8* __restrict__ src = (const bf16x8*)(WhP + (size_t)j0 * 57344);
        bf16x8* dst = (bf16x8*)whL;
        #pragma unroll
        for (int i = 0; i < 112; ++i) dst[i * 64 + lane] = src[i * 64 + lane];
    }
    __syncthreads();

    const int colL = lane & 15;
    const int b = grp * 16 + colL;                    // fixed batch per lane
    const int hcolBase = j0 * 16 + ((lane >> 4) << 2);
    const short* __restrict__ wlds = whL + lane * 8;  // + g*8192 + kt*512

    // consumer poll base voffset: unit (b, hcol4 = (lane>>4)*2 + kt*8 + {0,1})
    const unsigned pollBase = (unsigned)(b * 2048 + ((lane >> 4) << 5));
    // producer store voffset: unit (b, hcol4 = j0*4 + (lane>>4))
    const unsigned stOff = (unsigned)(b * 2048 + (j0 * 4 + (lane >> 4)) * 16);

    float cdecr[4] = {0.f, 0.f, 0.f, 0.f};
    float cbarr[4] = {0.f, 0.f, 0.f, 0.f};
    const size_t S = (size_t)BB * TT * HH;

    // deferred out-store registers (step t-1's outputs)
    f32x4 d_oc, d_ocb, d_od, d_oo;
    size_t d_ob = 0;

    // ---- prefetch t=0 gate row + dt ----
    unsigned long long xq[7];
    {
        const unsigned long long* xb64 =
            (const unsigned long long*)(Xb + (size_t)b * TT * NCOL + hcolBase);
        #pragma unroll
        for (int g = 0; g < 7; ++g) xq[g] = xb64[g * (HH / 4)];
    }
    float dtn = dur[b * TT + 1];

    #pragma unroll 1
    for (int t = 0; t < TT; ++t) {
        // ---- 1. acquire h_t: LL poll; success == data in registers ----
        u32x4 un[32];
        if (t > 0) {
            const void* sb = (const char*)hslots + (size_t)(t & 1) * SLOT_BYTES;
            const unsigned want = (unsigned)t;
            while (true) {
                #pragma unroll
                for (int kt = 0; kt < 16; ++kt) {
                    un[2 * kt]     = ld_unit_sc1(sb, pollBase + kt * 128);
                    un[2 * kt + 1] = ld_unit_sc1(sb, pollBase + kt * 128 + 16);
                }
                asm volatile("s_waitcnt vmcnt(0)" ::: "memory");
                __builtin_amdgcn_sched_barrier(0);
                bool ok = true;
                #pragma unroll
                for (int i = 0; i < 32; ++i) {
                    ok = ok && (un[i].y == want) && (un[i].w == want);
                }
                if (__all((int)ok)) break;
                __builtin_amdgcn_s_sleep(1);
            }
        } else {
            #pragma unroll
            for (int i = 0; i < 32; ++i) un[i] = (u32x4){0u, 0u, 0u, 0u};
        }

        // ---- 2. deferred out-stores of t-1 + prefetch t+1 (retire under
        //         GEMM; long gone before the publish store issues) ----
        if (t > 0) {
            *(f32x4*)(out + d_ob)         = d_oc;
            *(f32x4*)(out + d_ob + S)     = d_ocb;
            *(f32x4*)(out + d_ob + 2 * S) = d_od;
            *(f32x4*)(out + d_ob + 3 * S) = d_oo;
        }
        unsigned long long xqn[7];
        float dtnn;
        {
            const int tn = (t + 1 < TT) ? t + 1 : t;
            const unsigned long long* xb64n =
                (const unsigned long long*)(Xb + ((size_t)b * TT + tn) * NCOL + hcolBase);
            #pragma unroll
            for (int g = 0; g < 7; ++g) xqn[g] = xb64n[g * (HH / 4)];
            const int tn1 = (tn + 1 < TT) ? tn + 1 : TT - 1;
            dtnn = dur[b * TT + tn1];
        }

        // ---- 3. GEMM: 112 MFMAs, A from LDS, B from polled regs ----
        f32x4 acc[7];
        #pragma unroll
        for (int g = 0; g < 7; ++g) acc[g] = (f32x4){0.f, 0.f, 0.f, 0.f};

        #pragma unroll
        for (int kt = 0; kt < 16; ++kt) {
            union { unsigned d[4]; bf16x8 v; } u;
            u.d[0] = un[2 * kt].x;     u.d[1] = un[2 * kt].z;
            u.d[2] = un[2 * kt + 1].x; u.d[3] = un[2 * kt + 1].z;
            const short* wkt = wlds + kt * 512;
            #pragma unroll
            for (int g = 0; g < 7; ++g) {
                bf16x8 a = *(const bf16x8*)(wkt + g * 8192);
                acc[g] = __builtin_amdgcn_mfma_f32_16x16x32_bf16(a, u.v, acc[g], 0, 0, 0);
            }
        }

        // ---- 4. epilogue (per lane: batch b, hcols hcolBase..+3) ----
        f32x4 oc, ocb, od, oo;
        float hn_[4];
        #pragma unroll
        for (int r = 0; r < 4; ++r) {
            const float gi  = acc[0][r] + bf2f((short)(xq[0] >> (16 * r)));
            const float gf  = acc[1][r] + bf2f((short)(xq[1] >> (16 * r)));
            const float gz  = acc[2][r] + bf2f((short)(xq[2] >> (16 * r)));
            const float go  = acc[3][r] + bf2f((short)(xq[3] >> (16 * r)));
            const float gib = acc[4][r] + bf2f((short)(xq[4] >> (16 * r)));
            const float gfb = acc[5][r] + bf2f((short)(xq[5] >> (16 * r)));
            const float gd  = acc[6][r] + bf2f((short)(xq[6] >> (16 * r)));

            const float i_  = sigmoidf_(gi);
            const float f_  = sigmoidf_(gf);
            const float z_  = tanhf_(gz);
            const float o_  = sigmoidf_(go);
            const float ib_ = sigmoidf_(gib);
            const float fb_ = sigmoidf_(gfb);
            const float d_  = softplusf_(gd);

            const float c_new  = f_ * cdecr[r] + i_ * z_;
            const float cb_new = fb_ * cbarr[r] + ib_ * z_;

            oc[r] = c_new; ocb[r] = cb_new; od[r] = d_; oo[r] = o_;

            const float cdn = cb_new + (c_new - cb_new) * __expf(-d_ * dtn);
            hn_[r] = o_ * tanhf_(cdn);
            cdecr[r] = cdn;
            cbarr[r] = cb_new;
        }

        // ---- 5. publish h_{t+1}: ONE self-validating 16B store; no drain,
        //         no flag; the only VMEM op until the next poll ----
        if (t + 1 < TT) {
            u32x4 sv;
            sv.x = f2bf2(hn_[0], hn_[1]);
            sv.y = (unsigned)(t + 1);
            sv.z = f2bf2(hn_[2], hn_[3]);
            sv.w = (unsigned)(t + 1);
            void* sbn = (char*)hslots + (size_t)((t + 1) & 1) * SLOT_BYTES;
            st_unit_sc1(sbn, stOff, sv);
        }

        // ---- 6. roll state (registers only) ----
        d_oc = oc; d_ocb = ocb; d_od = od; d_oo = oo;
        d_ob = ((size_t)b * TT + t) * HH + hcolBase;
        #pragma unroll
        for (int g = 0; g < 7; ++g) xq[g] = xqn[g];
        dtn = dtnn;
    }

    // ---- final flush (t = TT-1 outputs) ----
    *(f32x4*)(out + d_ob)         = d_oc;
    *(f32x4*)(out + d_ob + S)     = d_ocb;
    *(f32x4*)(out + d_ob + 2 * S) = d_od;
    *(f32x4*)(out + d_ob + 3 * S) = d_oo;
}

extern "C" void kernel_launch(void* const* d_in, const int* in_sizes, int n_in,
                              void* d_out, int out_size, void* d_ws, size_t ws_size,
                              hipStream_t stream) {
    const float* input = (const float*)d_in[0];  // (B, T, D)
    const float* dur   = (const float*)d_in[1];  // (B, T)
    const float* Wx    = (const float*)d_in[2];  // (D, 7H)
    const float* Wh    = (const float*)d_in[3];  // (H, 7H)
    const float* bias  = (const float*)d_in[4];  // (7H,)
    float* out = (float*)d_out;                  // (4, B, T, H)

    short* Xb  = (short*)d_ws;                       // 45,875,200 shorts
    short* Xbf = Xb + (size_t)TT * BB * NCOL;        // 3,276,800
    short* WxP = Xbf + (size_t)BB * TT * DD;         // 917,504
    short* WhP = WxP + 224 * 8 * 64 * 8;             // 1,835,008
    unsigned* hslots = (unsigned*)(WhP + 32 * 7 * 16 * 64 * 8);  // 2*131072 B

    // slots must be zeroed every launch (seq=0 != any wanted t in [1,199])
    hipMemsetAsync(hslots, 0, 2 * SLOT_BYTES, stream);

    convert_x_kernel<<<3200, 256, 0, stream>>>(input, Xbf);
    pack_wx_kernel<<<3584, 256, 0, stream>>>(Wx, WxP);
    pack_wh_kernel<<<7168, 256, 0, stream>>>(Wh, WhP);

    precompute_kernel<<<dim3(28, 200), 256, 0, stream>>>(Xbf, WxP, bias, Xb);

    recurrent_kernel<<<NBLK, 64, 0, stream>>>(Xb, WhP, dur, hslots, out);
}